// Round 5
// baseline (595.934 us; speedup 1.0000x reference)
//
#include <hip/hip_runtime.h>
#include <math.h>

// EMRouting: B=8,H=12,W=12,K=3,CIN=16,COUT=32,P=16 -> 1152 positions x 144 votes
#define NPOS 1152
#define NN   144
#define COUTC 32
#define PP   16
#define EPSF 1e-7f
#define LOG2PI 1.8378770664093453f

#define MU_OFF   0
#define A_OFF    589824            // 1152*32*16
#define SIG_OFF  626688            // + 1152*32

typedef __attribute__((ext_vector_type(2))) __fp16    half2v;
typedef __attribute__((ext_vector_type(2))) float     f32x2;
typedef __attribute__((ext_vector_type(4))) float     f32x4;
typedef __attribute__((ext_vector_type(4))) unsigned  u32x4;

static __device__ __forceinline__ unsigned pk2(float a, float b) {
    half2v h = __builtin_amdgcn_cvt_pkrtz(a, b);   // v_cvt_pkrtz_f16_f32
    return __builtin_bit_cast(unsigned, h);
}
static __device__ __forceinline__ f32x2 upk(unsigned u) {
    half2v h = __builtin_bit_cast(half2v, u);
    f32x2 r; r.x = (float)h.x; r.y = (float)h.y;
    return r;
}

// Block = 256 threads = 4 waves. cout = tid&31, slot = tid>>5 (8 n-slots, n = slot+8j).
// Softmax over cout: 32-lane shuffle within each wave half. Pass 0 reads fp32 V
// non-temporally, writes fp16 copy to ws; passes 1-2 read fp16 (L2/L3-resident),
// software-pipelined x2 with packed-fp32 math.
template<int USE_HALF>
__global__ void __launch_bounds__(256, 4)   // allow ~128 VGPRs; grid gives ~4.5 blk/CU anyway
em_routing_kernel(const float* __restrict__ V,
                  const float* __restrict__ a,
                  const float* __restrict__ Bu,
                  const float* __restrict__ Ba,
                  const float* __restrict__ Rin,
                  float* __restrict__ out,
                  const u32x4* __restrict__ VhR,
                  u32x4* __restrict__ VhW)
{
    const int pos  = blockIdx.x;
    const int tid  = threadIdx.x;
    const int c    = tid & 31;
    const int slot = tid >> 5;
    const int wave = tid >> 6;

    const float* Vp = V + (size_t)pos * (NN * COUTC * PP);
    const float* Rp = Rin + (size_t)pos * (NN * COUTC);

    __shared__ float a_s[NN];
    __shared__ float red[4][COUTC][33];  // [0]=S0, [1..16]=S1, [17..32]=S2
    __shared__ float mu_s[COUTC][17];
    __shared__ float wp_s[COUTC][17];    // 1/(2*sigma^2+EPS)
    __shared__ float sg_s[COUTC][17];
    __shared__ float cl_s[COUTC];        // log(a_out) + log_p1
    __shared__ float ao_s[COUTC];

    for (int i = tid; i < NN; i += 256) a_s[i] = a[pos * NN + i];
    __syncthreads();

    const float lam_tab[3] = {0.01f * (1.f - 0.95f),
                              0.01f * (1.f - 0.95f * 0.95f),
                              0.01f * (1.f - 0.95f * 0.95f * 0.95f)};

    // ---- cross-wave reduce + per-cout finalize (2 barriers) ----
    auto reduce_finalize = [&](int it, float S0, f32x2 (&S1)[8], f32x2 (&S2)[8]) {
        S0 += __shfl_xor(S0, 32, 64);
        #pragma unroll
        for (int k = 0; k < 8; ++k) {
            S1[k].x += __shfl_xor(S1[k].x, 32, 64);
            S1[k].y += __shfl_xor(S1[k].y, 32, 64);
            S2[k].x += __shfl_xor(S2[k].x, 32, 64);
            S2[k].y += __shfl_xor(S2[k].y, 32, 64);
        }
        if ((tid & 32) == 0) {
            red[wave][c][0] = S0;
            #pragma unroll
            for (int k = 0; k < 8; ++k) {
                red[wave][c][1 + 2 * k]  = S1[k].x;
                red[wave][c][2 + 2 * k]  = S1[k].y;
                red[wave][c][17 + 2 * k] = S2[k].x;
                red[wave][c][18 + 2 * k] = S2[k].y;
            }
        }
        __syncthreads();
        if (tid < 32) {                       // 32 lanes do the whole finalize
            const int cc = tid;
            float d0 = red[0][cc][0] + red[1][cc][0] + red[2][cc][0] + red[3][cc][0];
            float inv = 1.f / (d0 + EPSF);
            float sumlog = 0.f;
            #pragma unroll
            for (int p = 0; p < PP; ++p) {
                float s1 = red[0][cc][1 + p]  + red[1][cc][1 + p]
                         + red[2][cc][1 + p]  + red[3][cc][1 + p];
                float s2 = red[0][cc][17 + p] + red[1][cc][17 + p]
                         + red[2][cc][17 + p] + red[3][cc][17 + p];
                float mu = s1 * inv;
                float sg = (s2 - 2.f * mu * s1 + mu * mu * d0) * inv;
                sg = fmaxf(sg, 1e-30f);       // guard cancellation
                mu_s[cc][p] = mu;
                sg_s[cc][p] = sg;
                wp_s[cc][p] = 1.f / (2.f * sg + EPSF);
                sumlog += __logf(sg);
            }
            float xv = lam_tab[it] * (Ba[cc] - d0 * (16.f * Bu[cc] + 0.5f * sumlog));
            float ss = xv * xv;               // L2 norm over 32 couts (lanes 0-31)
            #pragma unroll
            for (int m = 1; m <= 16; m <<= 1) ss += __shfl_xor(ss, m, 64);
            float y  = xv / fmaxf(sqrtf(ss), 1e-12f);
            float ao = 1.f / (1.f + __expf(-y));
            ao_s[cc] = ao;
            cl_s[cc] = __logf(ao) - 0.5f * (16.f * LOG2PI + sumlog) + EPSF;
        }
        __syncthreads();
    };

    // ---- pass 0: R from input; stream fp32 V (non-temporal), emit fp16 copy ----
    {
        float S0 = 0.f; f32x2 S1[8], S2[8];
        #pragma unroll
        for (int k = 0; k < 8; ++k) { S1[k] = (f32x2)0.f; S2[k] = (f32x2)0.f; }

        #pragma unroll 3
        for (int j = 0; j < 18; ++j) {
            const int n = slot + (j << 3);
            const f32x4* vp = (const f32x4*)(Vp + (size_t)n * (COUTC * PP) + c * PP);
            f32x4 q0 = __builtin_nontemporal_load(vp);
            f32x4 q1 = __builtin_nontemporal_load(vp + 1);
            f32x4 q2 = __builtin_nontemporal_load(vp + 2);
            f32x4 q3 = __builtin_nontemporal_load(vp + 3);
            f32x2 v2[8] = {{q0.x,q0.y},{q0.z,q0.w},{q1.x,q1.y},{q1.z,q1.w},
                           {q2.x,q2.y},{q2.z,q2.w},{q3.x,q3.y},{q3.z,q3.w}};
            if (USE_HALF) {
                size_t hb = ((size_t)(pos * NN + n) << 6) + (c << 1); // u32x4 units
                u32x4 u0, u1;
                u0.x = pk2(v2[0].x, v2[0].y); u0.y = pk2(v2[1].x, v2[1].y);
                u0.z = pk2(v2[2].x, v2[2].y); u0.w = pk2(v2[3].x, v2[3].y);
                u1.x = pk2(v2[4].x, v2[4].y); u1.y = pk2(v2[5].x, v2[5].y);
                u1.z = pk2(v2[6].x, v2[6].y); u1.w = pk2(v2[7].x, v2[7].y);
                VhW[hb] = u0; VhW[hb + 1] = u1;   // temporal: want these in L2/L3
            }
            float Rw = __builtin_nontemporal_load(Rp + n * COUTC + c) * a_s[n];
            S0 += Rw;
            f32x2 R2 = {Rw, Rw};
            #pragma unroll
            for (int k = 0; k < 8; ++k) {
                f32x2 w = v2[k] * v2[k];
                S1[k] += R2 * v2[k];
                S2[k] += R2 * w;
            }
        }
        reduce_finalize(0, S0, S1, S2);
    }

    // ---- passes 1,2: E-step softmax fused with next M-step ----
    for (int it = 1; it < 3; ++it) {
        f32x2 mu2[8], wp2[8];
        #pragma unroll
        for (int k = 0; k < 8; ++k) {
            mu2[k].x = mu_s[c][2 * k];     mu2[k].y = mu_s[c][2 * k + 1];
            wp2[k].x = wp_s[c][2 * k];     wp2[k].y = wp_s[c][2 * k + 1];
        }
        float cl_r = cl_s[c];

        float S0 = 0.f; f32x2 S1[8], S2[8];
        #pragma unroll
        for (int k = 0; k < 8; ++k) { S1[k] = (f32x2)0.f; S2[k] = (f32x2)0.f; }

        if (USE_HALF) {
            const size_t base = ((size_t)(pos * NN + slot) << 6) + (c << 1);
            // software pipeline: 9 groups of 2 n's, prefetch next group
            u32x4 A0 = VhR[base],       A1 = VhR[base + 1];
            u32x4 B0 = VhR[base + 512], B1 = VhR[base + 513];
            for (int jj = 0; jj < 9; ++jj) {
                size_t nb = base + (size_t)((jj < 8) ? (2 * jj + 2) : 0) * 512;
                u32x4 C0 = VhR[nb],       C1 = VhR[nb + 1];
                u32x4 D0 = VhR[nb + 512], D1 = VhR[nb + 513];
                const int n0 = slot + (jj << 4), n1 = n0 + 8;

                unsigned ua[8] = {A0.x,A0.y,A0.z,A0.w,A1.x,A1.y,A1.z,A1.w};
                unsigned ub[8] = {B0.x,B0.y,B0.z,B0.w,B1.x,B1.y,B1.z,B1.w};
                f32x2 va[8], vb[8];
                #pragma unroll
                for (int k = 0; k < 8; ++k) { va[k] = upk(ua[k]); vb[k] = upk(ub[k]); }

                f32x2 acc0 = (f32x2)0.f, acc1 = (f32x2)0.f;
                #pragma unroll
                for (int k = 0; k < 8; ++k) {
                    f32x2 d0 = va[k] - mu2[k]; acc0 += (d0 * d0) * wp2[k];
                    f32x2 d1 = vb[k] - mu2[k]; acc1 += (d1 * d1) * wp2[k];
                }
                float l0 = cl_r - (acc0.x + acc0.y);
                float l1 = cl_r - (acc1.x + acc1.y);
                float m0 = l0, m1 = l1;
                #pragma unroll
                for (int msk = 1; msk <= 16; msk <<= 1) {   // two chains interleave
                    m0 = fmaxf(m0, __shfl_xor(m0, msk, 64));
                    m1 = fmaxf(m1, __shfl_xor(m1, msk, 64));
                }
                float e0 = __expf(l0 - m0), e1 = __expf(l1 - m1);
                float s0 = e0, s1 = e1;
                #pragma unroll
                for (int msk = 1; msk <= 16; msk <<= 1) {
                    s0 += __shfl_xor(s0, msk, 64);
                    s1 += __shfl_xor(s1, msk, 64);
                }
                float Rw0 = (e0 / s0) * a_s[n0];
                float Rw1 = (e1 / s1) * a_s[n1];
                S0 += Rw0 + Rw1;
                f32x2 R0 = {Rw0, Rw0}, R1 = {Rw1, Rw1};
                #pragma unroll
                for (int k = 0; k < 8; ++k) {
                    S1[k] += R0 * va[k];
                    S2[k] += R0 * (va[k] * va[k]);
                    S1[k] += R1 * vb[k];
                    S2[k] += R1 * (vb[k] * vb[k]);
                }
                A0 = C0; A1 = C1; B0 = D0; B1 = D1;
            }
        } else {
            for (int j = 0; j < 18; ++j) {
                const int n = slot + (j << 3);
                const f32x4* vp = (const f32x4*)(Vp + (size_t)n * (COUTC * PP) + c * PP);
                f32x4 q0 = vp[0], q1 = vp[1], q2 = vp[2], q3 = vp[3];
                f32x2 va[8] = {{q0.x,q0.y},{q0.z,q0.w},{q1.x,q1.y},{q1.z,q1.w},
                               {q2.x,q2.y},{q2.z,q2.w},{q3.x,q3.y},{q3.z,q3.w}};
                f32x2 acc = (f32x2)0.f;
                #pragma unroll
                for (int k = 0; k < 8; ++k) {
                    f32x2 d = va[k] - mu2[k]; acc += (d * d) * wp2[k];
                }
                float logit = cl_r - (acc.x + acc.y);
                float m = logit;
                #pragma unroll
                for (int msk = 1; msk <= 16; msk <<= 1)
                    m = fmaxf(m, __shfl_xor(m, msk, 64));
                float e = __expf(logit - m);
                float sum = e;
                #pragma unroll
                for (int msk = 1; msk <= 16; msk <<= 1)
                    sum += __shfl_xor(sum, msk, 64);
                float Rw = (e / sum) * a_s[n];
                S0 += Rw;
                f32x2 R2 = {Rw, Rw};
                #pragma unroll
                for (int k = 0; k < 8; ++k) {
                    S1[k] += R2 * va[k];
                    S2[k] += R2 * (va[k] * va[k]);
                }
            }
        }
        reduce_finalize(it, S0, S1, S2);
    }

    // ---- outputs (from iteration 2's M-step) ----
    for (int idx = tid; idx < COUTC * PP; idx += 256) {
        int cc = idx >> 4, p = idx & 15;
        out[MU_OFF  + (size_t)pos * (COUTC * PP) + idx] = mu_s[cc][p];
        out[SIG_OFF + (size_t)pos * (COUTC * PP) + idx] = sg_s[cc][p];
    }
    if (tid < COUTC) out[A_OFF + pos * COUTC + tid] = ao_s[tid];
}

extern "C" void kernel_launch(void* const* d_in, const int* in_sizes, int n_in,
                              void* d_out, int out_size, void* d_ws, size_t ws_size,
                              hipStream_t stream) {
    const float* V  = (const float*)d_in[0];
    const float* a  = (const float*)d_in[1];
    const float* Bu = (const float*)d_in[2];
    const float* Ba = (const float*)d_in[3];
    const float* R  = (const float*)d_in[4];
    float* out = (float*)d_out;
    const size_t need = (size_t)NPOS * NN * COUTC * PP * 2;   // 162 MB fp16 V copy
    if (ws_size >= need) {
        em_routing_kernel<1><<<NPOS, 256, 0, stream>>>(V, a, Bu, Ba, R, out,
                                                       (const u32x4*)d_ws, (u32x4*)d_ws);
    } else {
        em_routing_kernel<0><<<NPOS, 256, 0, stream>>>(V, a, Bu, Ba, R, out,
                                                       (const u32x4*)d_ws, (u32x4*)d_ws);
    }
}